// Round 1
// 425.762 us; speedup vs baseline: 1.0740x; 1.0740x over previous
//
#include <hip/hip_runtime.h>

// FWHT of 16384 rows x 4096 fp32, times scalar scale.
// v2: 256 threads/block (4 waves), one row per block, 16 elems/thread.
//
// Why: v1 (64-thr blocks, 64 elems/lane) was latency-bound: ~17.5 KB LDS and
// ~100+ VGPRs capped residency at ~9 waves/CU, and the epilogue issued 64
// scalar stores/lane whose 64-lane footprint was 16 discontiguous 16B
// segments (4x request amplification). v2 trades one extra LDS transpose for
// 4x the occupancy (32 waves/CU), ~40 VGPRs, and fully dense loads+stores.
//
// Element index i (12 bits), three register passes of 4 bits each:
//   P1 on bits {0,1,10,11}  (load layout:  i = k*1024 + 4t + c,  regs r[k*4+c])
//   P2 on bits {2..5}       (after T1:     i = h*64 + 4m + c',   regs r[m])
//   P3 on bits {6..9}       (after T2:     i = w*1024 + g*64 + l, regs r[g])
// The final layout gives dense 256B-per-instruction scalar stores.
//
// LDS layout for both transposes: elem i lives at word A(i) = i + 4*(i>>6)
// (64-word rows padded to 68 words). All b32 accesses hit 2 lanes/bank
// (free, m136); the float4 ops (T1 write, T3-style read) are bank-balanced
// at 8 words/bank. T1-read and T2-write use the SAME per-thread addresses,
// so no barrier is needed between them: 2 barriers total.

__device__ __forceinline__ void bfly(float& a, float& b) {
  const float x = a, y = b;
  a = x + y;
  b = x - y;
}

__global__ __launch_bounds__(256, 8) void fwht_kernel(
    const float* __restrict__ x, const float* __restrict__ scale,
    float* __restrict__ out) {
  __shared__ __align__(16) float lds[4348];  // max A(4095) = 4347 words
  const int t = threadIdx.x;   // 0..255
  const int row = blockIdx.x;  // 0..16383
  const float* xr = x + (size_t)row * 4096;
  float* outr = out + (size_t)row * 4096;
  const float s = scale[0];

  float r[16];

  // ---- load: r[k*4+c] = x[k*1024 + 4t + c] — 4 dense float4 per thread ----
#pragma unroll
  for (int k = 0; k < 4; ++k) {
    const float4 f = *reinterpret_cast<const float4*>(xr + k * 1024 + 4 * t);
    r[k * 4 + 0] = f.x; r[k * 4 + 1] = f.y;
    r[k * 4 + 2] = f.z; r[k * 4 + 3] = f.w;
  }

  // ---- P1: butterflies on bits 0,1 (c) and 10,11 (k) ----
#pragma unroll
  for (int k = 0; k < 4; ++k) {
    bfly(r[k * 4 + 0], r[k * 4 + 1]); bfly(r[k * 4 + 2], r[k * 4 + 3]); // bit 0
    bfly(r[k * 4 + 0], r[k * 4 + 2]); bfly(r[k * 4 + 1], r[k * 4 + 3]); // bit 1
  }
#pragma unroll
  for (int c = 0; c < 4; ++c) {
    bfly(r[0 + c], r[4 + c]); bfly(r[8 + c], r[12 + c]);                // bit 10
    bfly(r[0 + c], r[8 + c]); bfly(r[4 + c], r[12 + c]);                // bit 11
  }

  // ---- T1 write: elem i = k*1024 + 4t + c -> A(i); one float4 per k ----
  {
    const int wb = 4 * t + 4 * (t >> 4);  // 4t plus row pad; multiple of 4
#pragma unroll
    for (int k = 0; k < 4; ++k) {
      *reinterpret_cast<float4*>(&lds[k * 1088 + wb]) =
          make_float4(r[k * 4 + 0], r[k * 4 + 1], r[k * 4 + 2], r[k * 4 + 3]);
    }
  }
  __syncthreads();

  // ---- T1 read: r[m] = elem h*64 + 4m + c'   (h = t>>2, c' = t&3) ----
  const int rb1 = (t >> 2) * 68 + (t & 3);
#pragma unroll
  for (int m = 0; m < 16; ++m) r[m] = lds[rb1 + 4 * m];

  // ---- P2: butterflies on bits 2..5 (m) ----
#pragma unroll
  for (int bit = 0; bit < 4; ++bit) {
    const int mask = 1 << bit;
#pragma unroll
    for (int m = 0; m < 16; ++m)
      if (!(m & mask)) bfly(r[m], r[m | mask]);
  }

  // ---- T2 write: same per-thread addresses as T1 read (no barrier needed
  //      in between: only the owning thread touches these words) ----
#pragma unroll
  for (int m = 0; m < 16; ++m) lds[rb1 + 4 * m] = r[m];
  __syncthreads();

  // ---- T2 read: r[g] = elem w*1024 + g*64 + l   (w = t>>6, l = t&63) ----
  const int rb2 = (t >> 6) * 1088 + (t & 63);
#pragma unroll
  for (int g = 0; g < 16; ++g) r[g] = lds[rb2 + 68 * g];

  // ---- P3: butterflies on bits 6..9 (g) ----
#pragma unroll
  for (int bit = 0; bit < 4; ++bit) {
    const int mask = 1 << bit;
#pragma unroll
    for (int g = 0; g < 16; ++g)
      if (!(g & mask)) bfly(r[g], r[g | mask]);
  }

  // ---- scale + store: 16 dense 256B-per-instruction scalar stores ----
  float* op = outr + (t >> 6) * 1024 + (t & 63);
#pragma unroll
  for (int g = 0; g < 16; ++g) op[g * 64] = r[g] * s;
}

extern "C" void kernel_launch(void* const* d_in, const int* in_sizes, int n_in,
                              void* d_out, int out_size, void* d_ws, size_t ws_size,
                              hipStream_t stream) {
  (void)in_sizes; (void)n_in; (void)d_ws; (void)ws_size; (void)out_size;
  const float* x = (const float*)d_in[0];
  const float* scale = (const float*)d_in[1];
  float* out = (float*)d_out;
  fwht_kernel<<<16384, 256, 0, stream>>>(x, scale, out);
}